// Round 9
// baseline (177.434 us; speedup 1.0000x reference)
//
#include <hip/hip_runtime.h>

#define NODE_IN 64
#define EDGE_IN 32
#define GLOBAL_IN 32
#define HID 128
#define EOUT 32

typedef float f32x4 __attribute__((ext_vector_type(4)));
typedef float f32x2 __attribute__((ext_vector_type(2)));
typedef short s16x8 __attribute__((ext_vector_type(8)));
typedef unsigned short u16x8 __attribute__((ext_vector_type(8)));

// LDS map: X bf16 [64][24 chunks of 16B] (384B rows; chunks 0-7 src, 8-15 dst,
// 16-23 ea; chunk-XOR swizzled, r8-verified 2-way) | H bf16 [64][16 chunks]
// (256B rows, chunk-XOR) | u bf16 [128][32] (64B rows, staged once per block).
#define XROW 384
#define HOFF 24576
#define UOFF 40960
#define LDSZ 49152

__device__ __forceinline__ unsigned short f2bf(float f) {
  __bf16 h = (__bf16)f;
  return __builtin_bit_cast(unsigned short, h);
}

__device__ __forceinline__ s16x8 cvt8(f32x4 a, f32x4 b) {
  u16x8 v = { f2bf(a[0]), f2bf(a[1]), f2bf(a[2]), f2bf(a[3]),
              f2bf(b[0]), f2bf(b[1]), f2bf(b[2]), f2bf(b[3]) };
  return __builtin_bit_cast(s16x8, v);
}

__device__ __forceinline__ void bar_lds() {   // lgkm-only barrier
  asm volatile("s_waitcnt lgkmcnt(0)" ::: "memory");
  __builtin_amdgcn_s_barrier();
  asm volatile("" ::: "memory");
}

// ---- prep: write W1/W2 as bf16 MFMA B-fragment tables into d_ws ----
// frag f<48: (kk=f>>3, wd=(f>>1)&3, nt=f&1): lane l elem j =
//   W1[(32kk+8(l>>4)+j)*128 + 32wd + 2(l&15) + nt]   (paired-col permutation)
// frag f>=48: q=f-48 (kk=q>>1, nt=q&1): W2[(32kk+8(l>>4)+j)*32 + 2(l&15)+nt]
__global__ __launch_bounds__(64) void prep_w(const float* __restrict__ W1,
                                             const float* __restrict__ W2,
                                             unsigned short* __restrict__ wsf) {
  const int f = blockIdx.x, l = threadIdx.x;
  const int lg = l >> 4, lr = l & 15;
  u16x8 v;
  if (f < 48) {
    const int kk = f >> 3, wd = (f >> 1) & 3, nt = f & 1;
#pragma unroll
    for (int j = 0; j < 8; ++j)
      v[j] = f2bf(W1[(32*kk + 8*lg + j)*HID + 32*wd + 2*lr + nt]);
  } else {
    const int q = f - 48, kk = q >> 1, nt = q & 1;
#pragma unroll
    for (int j = 0; j < 8; ++j)
      v[j] = f2bf(W2[(32*kk + 8*lg + j)*EOUT + 2*lr + nt]);
  }
  *(u16x8*)&wsf[f*512 + l*8] = v;
}

// ============================================================================
// Occupancy-first main kernel. gfx950's UNIFIED VGPR/AGPR file means weights-
// in-registers (rounds 1-8: ~250 regs/wave total) capped residency at ~8
// waves/CU — the invariant 21% occupancy. Here weights stream from the d_ws
// fragment table (1 coalesced 16B load/lane, 2 live frags, unroll-1 k-loops),
// u is block-staged, no register prefetch: footprint ~110/wave, LDS 48KB ->
// 12 waves/CU. TLP replaces manual pipelining.
// ============================================================================
__global__ __launch_bounds__(256) void edge_mlp(
    const float* __restrict__ srcp, const float* __restrict__ dstp,
    const float* __restrict__ eap, const float* __restrict__ up,
    const int* __restrict__ ebp, const unsigned short* __restrict__ wsf,
    const float* __restrict__ b1, const float* __restrict__ b2,
    float* __restrict__ outp, int E, int ntiles)
{
  __shared__ __align__(16) char SM[LDSZ];

  const int t = threadIdx.x;
  const int wid = t >> 6;
  const int lane = t & 63;
  const int g = lane >> 4;
  const int r16 = lane & 15;
  const int rA = t >> 3, cA8 = (t & 7) * 8;
  const int rC = t >> 2, cC8 = (t & 3) * 8;
  const int Em1 = E - 1;

  const float b1v0 = b1[32*wid + 2*r16];
  const float b1v1 = b1[32*wid + 2*r16 + 1];
  const float b2v0 = b2[2*r16];
  const float b2v1 = b2[2*r16 + 1];

  // write-side chunk swizzle (involution: chunk ^= row&7 within 8-groups)
  const int sxw = (t & 7) ^ (rA & 7);
  const int sew = (t & 3) ^ (rC & 7);

  // ---- stage u once: f32[128][32] -> bf16 LDS [128][32] ----
  {
    const int row = t >> 1, half = t & 1;
    const float* pu = up + row * GLOBAL_IN + half * 16;
    const f32x4 u0 = *(const f32x4*)pu,       u1 = *(const f32x4*)(pu + 4);
    const f32x4 u2 = *(const f32x4*)(pu + 8), u3 = *(const f32x4*)(pu + 12);
    *(s16x8*)(SM + UOFF + row*64 + half*32)      = cvt8(u0, u1);
    *(s16x8*)(SM + UOFF + row*64 + half*32 + 16) = cvt8(u2, u3);
  }

  int bb0, bb1, bb2, bb3;
  auto load_bb = [&](int tb) {
    bb0 = ebp[min(tb + r16,      Em1)];
    bb1 = ebp[min(tb + 16 + r16, Em1)];
    bb2 = ebp[min(tb + 32 + r16, Em1)];
    bb3 = ebp[min(tb + 48 + r16, Em1)];
  };

  auto stage_x = [&](int tb) {
    const int r0 = min(tb + rA, Em1);
    const int r1 = min(tb + 32 + rA, Em1);
    const int r2 = min(tb + rC, Em1);
    const float* s0 = srcp + (size_t)r0 * NODE_IN + cA8;
    const float* s1 = srcp + (size_t)r1 * NODE_IN + cA8;
    const float* d0 = dstp + (size_t)r0 * NODE_IN + cA8;
    const float* d1 = dstp + (size_t)r1 * NODE_IN + cA8;
    const float* e0 = eap  + (size_t)r2 * EDGE_IN + cC8;
    const f32x4 q0 = *(const f32x4*)s0, q1 = *(const f32x4*)(s0 + 4);
    const f32x4 q2 = *(const f32x4*)s1, q3 = *(const f32x4*)(s1 + 4);
    const f32x4 q4 = *(const f32x4*)d0, q5 = *(const f32x4*)(d0 + 4);
    const f32x4 q6 = *(const f32x4*)d1, q7 = *(const f32x4*)(d1 + 4);
    const f32x4 q8 = *(const f32x4*)e0, q9 = *(const f32x4*)(e0 + 4);
    *(s16x8*)(SM + rA*XROW        + sxw*16)     = cvt8(q0, q1);
    *(s16x8*)(SM + (rA+32)*XROW   + sxw*16)     = cvt8(q2, q3);
    *(s16x8*)(SM + rA*XROW        + (8+sxw)*16) = cvt8(q4, q5);
    *(s16x8*)(SM + (rA+32)*XROW   + (8+sxw)*16) = cvt8(q6, q7);
    *(s16x8*)(SM + rC*XROW        + (16+sew)*16)= cvt8(q8, q9);
  };

  int tile = blockIdx.x;
  const int TS = gridDim.x;

  stage_x(tile * 64);
  load_bb(tile * 64);
  bar_lds();                         // X(t0) + u staged

  const int s = r16 & 7;

  for (; tile < ntiles; tile += TS) {
    const int mbase = tile * 64;

    // ---- layer 1: K=192 as 6 kk-steps (unroll-1: 2 live w-frags) ----
    f32x4 acc[4][2];
    {
      const f32x4 z = {0.f, 0.f, 0.f, 0.f};
#pragma unroll
      for (int mi = 0; mi < 4; ++mi) { acc[mi][0] = z; acc[mi][1] = z; }
    }
#pragma unroll 1
    for (int kk = 0; kk < 6; ++kk) {
      const s16x8 w0 = *(const s16x8*)&wsf[(kk*8 + wid*2 + 0)*512 + lane*8];
      const s16x8 w1 = *(const s16x8*)&wsf[(kk*8 + wid*2 + 1)*512 + lane*8];
      s16x8 f0, f1, f2, f3;
      if (kk == 5) {                 // u segment, from block-staged u_lds
        f0 = *(const s16x8*)(SM + UOFF + bb0*64 + g*16);
        f1 = *(const s16x8*)(SM + UOFF + bb1*64 + g*16);
        f2 = *(const s16x8*)(SM + UOFF + bb2*64 + g*16);
        f3 = *(const s16x8*)(SM + UOFF + bb3*64 + g*16);
      } else {                       // X segment, swizzled chunk
        const int phys = ((kk >> 1) << 3) + ((4*(kk & 1) + g) ^ s);
        const char* base = SM + phys*16;
        f0 = *(const s16x8*)(base + (r16     )*XROW);
        f1 = *(const s16x8*)(base + (16 + r16)*XROW);
        f2 = *(const s16x8*)(base + (32 + r16)*XROW);
        f3 = *(const s16x8*)(base + (48 + r16)*XROW);
      }
      acc[0][0] = __builtin_amdgcn_mfma_f32_16x16x32_bf16(f0, w0, acc[0][0], 0, 0, 0);
      acc[0][1] = __builtin_amdgcn_mfma_f32_16x16x32_bf16(f0, w1, acc[0][1], 0, 0, 0);
      acc[1][0] = __builtin_amdgcn_mfma_f32_16x16x32_bf16(f1, w0, acc[1][0], 0, 0, 0);
      acc[1][1] = __builtin_amdgcn_mfma_f32_16x16x32_bf16(f1, w1, acc[1][1], 0, 0, 0);
      acc[2][0] = __builtin_amdgcn_mfma_f32_16x16x32_bf16(f2, w0, acc[2][0], 0, 0, 0);
      acc[2][1] = __builtin_amdgcn_mfma_f32_16x16x32_bf16(f2, w1, acc[2][1], 0, 0, 0);
      acc[3][0] = __builtin_amdgcn_mfma_f32_16x16x32_bf16(f3, w0, acc[3][0], 0, 0, 0);
      acc[3][1] = __builtin_amdgcn_mfma_f32_16x16x32_bf16(f3, w1, acc[3][1], 0, 0, 0);
    }

    // ---- epilogue: +b1, relu, packed dword -> swizzled H ----
#pragma unroll
    for (int mi = 0; mi < 4; ++mi) {
#pragma unroll
      for (int j = 0; j < 4; ++j) {
        const float h0 = fmaxf(acc[mi][0][j] + b1v0, 0.f);
        const float h1 = fmaxf(acc[mi][1][j] + b1v1, 0.f);
        const unsigned int pk = (unsigned int)f2bf(h0) |
                                ((unsigned int)f2bf(h1) << 16);
        const int row = 16*mi + 4*g + j;
        const int ch = (4*wid + (r16 >> 2)) ^ ((4*g + j) & 7);
        *(unsigned int*)(SM + HOFF + row*256 + ch*16 + (r16 & 3)*4) = pk;
      }
    }
    bar_lds();                       // B1: H ready; X reads done

    // ---- layer 2: K=128 as 4 kk-steps, w2 frags streamed ----
    f32x4 a20, a21;
    { const f32x4 z = {0.f, 0.f, 0.f, 0.f}; a20 = z; a21 = z; }
#pragma unroll 1
    for (int kk2 = 0; kk2 < 4; ++kk2) {
      const s16x8 v0 = *(const s16x8*)&wsf[(48 + kk2*2 + 0)*512 + lane*8];
      const s16x8 v1 = *(const s16x8*)&wsf[(48 + kk2*2 + 1)*512 + lane*8];
      const int ch = (4*kk2 + g) ^ s;
      const s16x8 ah = *(const s16x8*)(SM + HOFF + (16*wid + r16)*256 + ch*16);
      a20 = __builtin_amdgcn_mfma_f32_16x16x32_bf16(ah, v0, a20, 0, 0, 0);
      a21 = __builtin_amdgcn_mfma_f32_16x16x32_bf16(ah, v1, a21, 0, 0, 0);
    }
#pragma unroll
    for (int j = 0; j < 4; ++j) {
      const int m = mbase + 16*wid + 4*g + j;
      if (m < E) {
        f32x2 o = { a20[j] + b2v0, a21[j] + b2v1 };
        *(f32x2*)(outp + (size_t)m*EOUT + 2*r16) = o;
      }
    }

    // ---- stage next tile (X reads done at B1; H-WAR covered by next B0) ----
    stage_x((tile + TS) * 64);
    load_bb((tile + TS) * 64);
    bar_lds();                       // B0: X(t+1) ready
  }
}

extern "C" void kernel_launch(void* const* d_in, const int* in_sizes, int n_in,
                              void* d_out, int out_size, void* d_ws, size_t ws_size,
                              hipStream_t stream) {
  const float* srcp = (const float*)d_in[0];
  const float* dstp = (const float*)d_in[1];
  const float* eap  = (const float*)d_in[2];
  const float* up   = (const float*)d_in[3];
  const int*   ebp  = (const int*)d_in[4];
  const float* W1   = (const float*)d_in[5];
  const float* b1   = (const float*)d_in[6];
  const float* W2   = (const float*)d_in[7];
  const float* b2   = (const float*)d_in[8];
  float* outp = (float*)d_out;
  unsigned short* wsf = (unsigned short*)d_ws;

  const int E = in_sizes[0] / NODE_IN;
  const int ntiles = (E + 63) / 64;
  const int grid = ntiles < 2048 ? ntiles : 2048;

  prep_w<<<56, 64, 0, stream>>>(W1, W2, wsf);
  edge_mlp<<<grid, 256, 0, stream>>>(srcp, dstp, eap, up, ebp, wsf, b1, b2,
                                     outp, E, ntiles);
}

// Round 10
// 162.234 us; speedup vs baseline: 1.0937x; 1.0937x over previous
//
#include <hip/hip_runtime.h>

#define NODE_IN 64
#define EDGE_IN 32
#define GLOBAL_IN 32
#define HID 128
#define EOUT 32

typedef float f32x4 __attribute__((ext_vector_type(4)));
typedef float f32x2 __attribute__((ext_vector_type(2)));
typedef short s16x8 __attribute__((ext_vector_type(8)));
typedef unsigned short u16x8 __attribute__((ext_vector_type(8)));

// LDS: X bf16 [64][192] (384 B rows, 24 x 16B chunks: src 0-7 | dst 8-15 |
// ea 16-23, chunk-XOR swizzled -> 2-way, r8-verified conflicts 8.1M->2.1M)
// + H bf16 [64][128] (256 B rows, chunk-XOR swizzled).
#define XROW 384
#define HOFF 24576
#define LDSZ 40960

// volatile asm loads: regalloc can NOT sink or delete these (rounds 5/6
// evidence: non-volatile prefetch was sunk to use).
#define GLOADX4(dst, ptr) asm volatile("global_load_dwordx4 %0, %1, off" : "=v"(dst) : "v"(ptr))
#define GLOADD(dst, ptr)  asm volatile("global_load_dword %0, %1, off"   : "=v"(dst) : "v"(ptr))

__device__ __forceinline__ unsigned short f2bf(float f) {
  __bf16 h = (__bf16)f;
  return __builtin_bit_cast(unsigned short, h);
}

__device__ __forceinline__ s16x8 cvt8(f32x4 a, f32x4 b) {
  u16x8 v = { f2bf(a[0]), f2bf(a[1]), f2bf(a[2]), f2bf(a[3]),
              f2bf(b[0]), f2bf(b[1]), f2bf(b[2]), f2bf(b[3]) };
  return __builtin_bit_cast(s16x8, v);
}

__device__ __forceinline__ void bar_lds() {     // lgkm-only barrier (T4)
  asm volatile("s_waitcnt lgkmcnt(0)" ::: "memory");
  __builtin_amdgcn_s_barrier();
  asm volatile("" ::: "memory");
}

// ---- prep: W1/W2 -> bf16 MFMA B-fragment table in d_ws (56 KB) ----
// frag f<48 (kk=f>>3, wd=(f>>1)&3, nt=f&1): lane l elem j =
//   W1[(32kk+8(l>>4)+j)*128 + 32wd + 2(l&15) + nt]    (paired-col perm)
// frag f>=48 (q=f-48, kk=q>>1, nt=q&1): W2[(32kk+8(l>>4)+j)*32 + 2(l&15)+nt]
__global__ __launch_bounds__(64) void prep_w(const float* __restrict__ W1,
                                             const float* __restrict__ W2,
                                             unsigned short* __restrict__ wsf) {
  const int f = blockIdx.x, l = threadIdx.x;
  const int lg = l >> 4, lr = l & 15;
  u16x8 v;
  if (f < 48) {
    const int kk = f >> 3, wd = (f >> 1) & 3, nt = f & 1;
#pragma unroll
    for (int j = 0; j < 8; ++j)
      v[j] = f2bf(W1[(32*kk + 8*lg + j)*HID + 32*wd + 2*lr + nt]);
  } else {
    const int q = f - 48, kk = q >> 1, nt = q & 1;
#pragma unroll
    for (int j = 0; j < 8; ++j)
      v[j] = f2bf(W2[(32*kk + 8*lg + j)*EOUT + 2*lr + nt]);
  }
  *(u16x8*)&wsf[f*512 + l*8] = v;
}

// ============================================================================
// R8 structure (pinned volatile-asm prefetch, swizzled X/H, 2 lgkm barriers)
// with the per-block weight prologue fixed: 20 coalesced b128 table loads
// (was 160 uncoalesced stride-512B loads) and grid=512 (= exactly 2 resident
// blocks/CU) so each CU pays ONE prologue + ~30.5 tiles instead of 4
// generations x (prologue + 7.6 tiles).
// ============================================================================
__global__ __launch_bounds__(256) void edge_mlp(
    const float* __restrict__ srcp, const float* __restrict__ dstp,
    const float* __restrict__ eap, const float* __restrict__ up,
    const int* __restrict__ ebp, const unsigned short* __restrict__ wsf,
    const float* __restrict__ b1, const float* __restrict__ b2,
    float* __restrict__ outp, int E, int ntiles)
{
  __shared__ __align__(16) char SM[LDSZ];

  const int t = threadIdx.x;
  const int wid = t >> 6;
  const int lane = t & 63;
  const int g = lane >> 4;
  const int r16 = lane & 15;
  const int rA = t >> 3, cA8 = (t & 7) * 8;   // src/dst staging rows rA, rA+32
  const int rC = t >> 2, cC8 = (t & 3) * 8;   // ea/u staging row
  const int Em1 = E - 1;

  // ---- weight fragments: coalesced b128 loads from the prep table ----
  s16x8 w1f[6][2];
#pragma unroll
  for (int kk = 0; kk < 6; ++kk) {
    w1f[kk][0] = *(const s16x8*)&wsf[(kk*8 + wid*2 + 0)*512 + lane*8];
    w1f[kk][1] = *(const s16x8*)&wsf[(kk*8 + wid*2 + 1)*512 + lane*8];
  }
  s16x8 w2f[4][2];
#pragma unroll
  for (int kk = 0; kk < 4; ++kk) {
    w2f[kk][0] = *(const s16x8*)&wsf[(48 + kk*2 + 0)*512 + lane*8];
    w2f[kk][1] = *(const s16x8*)&wsf[(48 + kk*2 + 1)*512 + lane*8];
  }
  const float b1v0 = b1[32*wid + 2*r16];
  const float b1v1 = b1[32*wid + 2*r16 + 1];
  const float b2v0 = b2[2*r16];
  const float b2v1 = b2[2*r16 + 1];

  // ---- pinned prefetch registers (one 64-edge tile slice / thread) ----
  f32x4 P0, P1, P2, P3, P4, P5, P6, P7, P8, P9, P10, P11;

  auto issue_gloads = [&](int mb, int eb) {
    const int r0 = min(mb + rA, Em1);
    const int r1 = min(mb + 32 + rA, Em1);
    const int r2 = min(mb + rC, Em1);
    const float* s0 = srcp + (size_t)r0 * NODE_IN + cA8;
    const float* s1 = srcp + (size_t)r1 * NODE_IN + cA8;
    const float* d0 = dstp + (size_t)r0 * NODE_IN + cA8;
    const float* d1 = dstp + (size_t)r1 * NODE_IN + cA8;
    const float* e0 = eap  + (size_t)r2 * EDGE_IN + cC8;
    const float* u0 = up   + (size_t)eb * GLOBAL_IN + cC8;
    GLOADX4(P0, s0);  GLOADX4(P1, s0 + 4);
    GLOADX4(P2, s1);  GLOADX4(P3, s1 + 4);
    GLOADX4(P4, d0);  GLOADX4(P5, d0 + 4);
    GLOADX4(P6, d1);  GLOADX4(P7, d1 + 4);
    GLOADX4(P8, e0);  GLOADX4(P9, e0 + 4);
    GLOADX4(P10, u0); GLOADX4(P11, u0 + 4);
  };

  // write-side chunk swizzle (involution c ^= row&7 within each 8-group)
  const int sxw = (t & 7) ^ (rA & 7);
  const int sew = ((t & 3)     ) ^ (rC & 7);
  const int suw = (4 + (t & 3) ) ^ (rC & 7);
  auto write_x = [&]() {
    *(s16x8*)(SM + rA*XROW        + sxw*16)        = cvt8(P0, P1);
    *(s16x8*)(SM + (rA+32)*XROW   + sxw*16)        = cvt8(P2, P3);
    *(s16x8*)(SM + rA*XROW        + (8+sxw)*16)    = cvt8(P4, P5);
    *(s16x8*)(SM + (rA+32)*XROW   + (8+sxw)*16)    = cvt8(P6, P7);
    *(s16x8*)(SM + rC*XROW        + (16+sew)*16)   = cvt8(P8, P9);
    *(s16x8*)(SM + rC*XROW        + (16+suw)*16)   = cvt8(P10, P11);
  };

  int tile = blockIdx.x;
  const int TS = gridDim.x;
  int ebv;

  // ---- prologue ----
  {
    const int eb0 = ebp[min(tile*64 + rC, Em1)];
    const int eb1 = ebp[min((tile + TS)*64 + rC, Em1)];
    issue_gloads(tile * 64, eb0);
    asm volatile("s_waitcnt vmcnt(0)" ::: "memory");
    __builtin_amdgcn_sched_barrier(0);
    write_x();                                  // SMX = tile0
    issue_gloads((tile + TS) * 64, eb1);        // tile1 in flight
    GLOADD(ebv, (ebp + min((tile + 2*TS)*64 + rC, Em1)));
  }
  bar_lds();                                    // X(tile0) staged

  for (; tile < ntiles; tile += TS) {
    const int mbase = tile * 64;

    // ---- layer 1: 4 m-tiles x 2 n-frags, K=192, swizzled SMX reads ----
    f32x4 acc[4][2];
    {
      const f32x4 z = {0.f, 0.f, 0.f, 0.f};
#pragma unroll
      for (int mi = 0; mi < 4; ++mi) { acc[mi][0] = z; acc[mi][1] = z; }
    }
#pragma unroll
    for (int mi = 0; mi < 4; ++mi) {
      const int r = 16*mi + r16;
      const char* Rp = SM + r * XROW;
      const int s = r16 & 7;
      const s16x8 f0 = *(const s16x8*)(Rp + ((g     ^ s)      )*16);
      const s16x8 f1 = *(const s16x8*)(Rp + (((4+g) ^ s)      )*16);
      const s16x8 f2 = *(const s16x8*)(Rp + ((g     ^ s) +  8 )*16);
      const s16x8 f3 = *(const s16x8*)(Rp + (((4+g) ^ s) +  8 )*16);
      const s16x8 f4 = *(const s16x8*)(Rp + ((g     ^ s) + 16 )*16);
      const s16x8 f5 = *(const s16x8*)(Rp + (((4+g) ^ s) + 16 )*16);
      acc[mi][0] = __builtin_amdgcn_mfma_f32_16x16x32_bf16(f0, w1f[0][0], acc[mi][0], 0, 0, 0);
      acc[mi][1] = __builtin_amdgcn_mfma_f32_16x16x32_bf16(f0, w1f[0][1], acc[mi][1], 0, 0, 0);
      acc[mi][0] = __builtin_amdgcn_mfma_f32_16x16x32_bf16(f1, w1f[1][0], acc[mi][0], 0, 0, 0);
      acc[mi][1] = __builtin_amdgcn_mfma_f32_16x16x32_bf16(f1, w1f[1][1], acc[mi][1], 0, 0, 0);
      acc[mi][0] = __builtin_amdgcn_mfma_f32_16x16x32_bf16(f2, w1f[2][0], acc[mi][0], 0, 0, 0);
      acc[mi][1] = __builtin_amdgcn_mfma_f32_16x16x32_bf16(f2, w1f[2][1], acc[mi][1], 0, 0, 0);
      acc[mi][0] = __builtin_amdgcn_mfma_f32_16x16x32_bf16(f3, w1f[3][0], acc[mi][0], 0, 0, 0);
      acc[mi][1] = __builtin_amdgcn_mfma_f32_16x16x32_bf16(f3, w1f[3][1], acc[mi][1], 0, 0, 0);
      acc[mi][0] = __builtin_amdgcn_mfma_f32_16x16x32_bf16(f4, w1f[4][0], acc[mi][0], 0, 0, 0);
      acc[mi][1] = __builtin_amdgcn_mfma_f32_16x16x32_bf16(f4, w1f[4][1], acc[mi][1], 0, 0, 0);
      acc[mi][0] = __builtin_amdgcn_mfma_f32_16x16x32_bf16(f5, w1f[5][0], acc[mi][0], 0, 0, 0);
      acc[mi][1] = __builtin_amdgcn_mfma_f32_16x16x32_bf16(f5, w1f[5][1], acc[mi][1], 0, 0, 0);
    }

    // ---- epilogue: +b1, relu, packed dword -> swizzled H ----
#pragma unroll
    for (int mi = 0; mi < 4; ++mi) {
#pragma unroll
      for (int j = 0; j < 4; ++j) {
        const float h0 = fmaxf(acc[mi][0][j] + b1v0, 0.f);
        const float h1 = fmaxf(acc[mi][1][j] + b1v1, 0.f);
        const unsigned int pk = (unsigned int)f2bf(h0) |
                                ((unsigned int)f2bf(h1) << 16);
        const int row = 16*mi + 4*g + j;
        const int ch = (4*wid + (r16 >> 2)) ^ ((4*g + j) & 7);
        *(unsigned int*)(SM + HOFF + row*256 + ch*16 + (r16 & 3)*4) = pk;
      }
    }
    bar_lds();          // B1: H ready; all SMX(t) reads done

    // ---- stage tile+TS (P arrived ~1 iteration ago -> near-free wait) ----
    asm volatile("s_waitcnt vmcnt(0)" ::: "memory");
    __builtin_amdgcn_sched_barrier(0);
    write_x();
    issue_gloads((tile + 2*TS) * 64, ebv);      // flies over L2 + next L1
    GLOADD(ebv, (ebp + min((tile + 3*TS)*64 + rC, Em1)));

    // ---- layer 2: 16 rows/wave, K=128, swizzled H reads ----
    f32x4 acc2[2];
    {
      const f32x4 z = {0.f, 0.f, 0.f, 0.f};
      acc2[0] = z; acc2[1] = z;
    }
#pragma unroll
    for (int kk = 0; kk < 4; ++kk) {
      const int ch = (4*kk + g) ^ (r16 & 7);
      const s16x8 ah = *(const s16x8*)(SM + HOFF + (16*wid + r16)*256 + ch*16);
      acc2[0] = __builtin_amdgcn_mfma_f32_16x16x32_bf16(ah, w2f[kk][0], acc2[0], 0, 0, 0);
      acc2[1] = __builtin_amdgcn_mfma_f32_16x16x32_bf16(ah, w2f[kk][1], acc2[1], 0, 0, 0);
    }
#pragma unroll
    for (int j = 0; j < 4; ++j) {
      const int m = mbase + 16*wid + 4*g + j;
      if (m < E) {
        f32x2 o = { acc2[0][j] + b2v0, acc2[1][j] + b2v1 };
        *(f32x2*)(outp + (size_t)m*EOUT + 2*r16) = o;
      }
    }
    bar_lds();          // B2: SMX(t+1) staged; H reads done (WAR for next epi)
  }
}

extern "C" void kernel_launch(void* const* d_in, const int* in_sizes, int n_in,
                              void* d_out, int out_size, void* d_ws, size_t ws_size,
                              hipStream_t stream) {
  const float* srcp = (const float*)d_in[0];
  const float* dstp = (const float*)d_in[1];
  const float* eap  = (const float*)d_in[2];
  const float* up   = (const float*)d_in[3];
  const int*   ebp  = (const int*)d_in[4];
  const float* W1   = (const float*)d_in[5];
  const float* b1   = (const float*)d_in[6];
  const float* W2   = (const float*)d_in[7];
  const float* b2   = (const float*)d_in[8];
  float* outp = (float*)d_out;
  unsigned short* wsf = (unsigned short*)d_ws;

  const int E = in_sizes[0] / NODE_IN;
  const int ntiles = (E + 63) / 64;
  // grid = 512 = exactly 2 resident blocks/CU (R8 occupancy proves 2 fit):
  // one generation, one weight prologue per CU, ~30.5 tiles/block.
  const int grid = ntiles < 512 ? ntiles : 512;

  prep_w<<<56, 64, 0, stream>>>(W1, W2, wsf);
  edge_mlp<<<grid, 256, 0, stream>>>(srcp, dstp, eap, up, ebp, wsf, b1, b2,
                                     outp, E, ntiles);
}